// Round 6
// baseline (162.980 us; speedup 1.0000x reference)
//
#include <hip/hip_runtime.h>
#include <hip/hip_bf16.h>
#include <math.h>

// Problem: B=2,H=16,SQ=SK=2048,D=M=128
#define NBH   32
#define SEQ   2048
#define DD    128
#define MM    128

typedef unsigned short u16;
typedef unsigned int   u32;
typedef unsigned char  u8;
typedef float  f32x4  __attribute__((ext_vector_type(4)));
typedef __bf16 bf16x8 __attribute__((ext_vector_type(8)));

#define SCALE_F 0.009791516697777346f  // sqrt(pi/2)/128
#define TAU 0.18f
#define CCAP 2048                      // per-block candidate cap (expected ~210)

// ---------- helpers ----------
static __device__ __forceinline__ u16 f2bf(float f) {
  union { float f; u32 u; } v; v.f = f;
  u32 u = v.u;
  u += 0x7fffu + ((u >> 16) & 1u);   // RNE
  return (u16)(u >> 16);
}

// exact-sign f64 dot of K row (global) with S row m; returns 1 if negative
static __device__ __forceinline__ u32 f64_negbit(const float* __restrict__ K,
                                                 const float* __restrict__ S,
                                                 int row_g, int m) {
  const f32x4* kr = (const f32x4*)(K + (size_t)row_g * DD);
  const f32x4* sr = (const f32x4*)(S + (size_t)m * DD);
  double a0 = 0, a1 = 0, a2 = 0, a3 = 0;
#pragma unroll
  for (int d = 0; d < 32; d += 4) {
    f32x4 x0 = kr[d],   y0 = sr[d];
    f32x4 x1 = kr[d+1], y1 = sr[d+1];
    f32x4 x2 = kr[d+2], y2 = sr[d+2];
    f32x4 x3 = kr[d+3], y3 = sr[d+3];
    a0 += (double)x0.x*y0.x + (double)x0.y*y0.y + (double)x0.z*y0.z + (double)x0.w*y0.w;
    a1 += (double)x1.x*y1.x + (double)x1.y*y1.y + (double)x1.z*y1.z + (double)x1.w*y1.w;
    a2 += (double)x2.x*y2.x + (double)x2.y*y2.y + (double)x2.z*y2.z + (double)x2.w*y2.w;
    a3 += (double)x3.x*y3.x + (double)x3.y*y3.y + (double)x3.z*y3.z + (double)x3.w*y3.w;
  }
  return (((a0 + a1) + (a2 + a3)) < 0.0) ? 1u : 0u;
}

// MFMA on two bf16 LDS tiles (k_proj: B = S). LDS layout: [row][chunk16B],
// chunk stored at (c ^ (row&7)).
static __device__ __forceinline__ void mfma_tile(const u16* lA, const u16* lB,
                                                 int wave, int lane,
                                                 f32x4 acc[4][4]) {
  const int wr = wave >> 1, wc = wave & 1;
  const int lrow = lane & 15, lkg = lane >> 4;
#pragma unroll
  for (int kk = 0; kk < 4; ++kk) {
    bf16x8 af[4], bfr[4];
    const int c = kk * 4 + lkg;
#pragma unroll
    for (int a = 0; a < 4; ++a) {
      const int r  = wr * 64 + a * 16 + lrow;
      const int r2 = wc * 64 + a * 16 + lrow;
      af[a]  = *(const bf16x8*)((const char*)lA + r  * 256 + ((c ^ (r  & 7)) << 4));
      bfr[a] = *(const bf16x8*)((const char*)lB + r2 * 256 + ((c ^ (r2 & 7)) << 4));
    }
#pragma unroll
    for (int a = 0; a < 4; ++a)
#pragma unroll
      for (int b = 0; b < 4; ++b)
        acc[a][b] = __builtin_amdgcn_mfma_f32_16x16x32_bf16(af[a], bfr[b], acc[a][b], 0, 0, 0);
  }
}

// stage a 128x128 f32 matrix (row-major, ld=128) into swizzled bf16 LDS
static __device__ __forceinline__ void stage_f32_to_bf16(const float* __restrict__ src,
                                                         u16* lds, int tid) {
#pragma unroll
  for (int j = 0; j < 8; ++j) {
    int i = tid + j * 256;             // bf16 16B-chunk index
    int r = i >> 4, c = i & 15;
    const f32x4* gp = (const f32x4*)(src + (size_t)r * DD + c * 8);
    f32x4 v0 = gp[0], v1 = gp[1];
    union { u16 h[8]; f32x4 v; } pk;
    pk.h[0] = f2bf(v0.x); pk.h[1] = f2bf(v0.y); pk.h[2] = f2bf(v0.z); pk.h[3] = f2bf(v0.w);
    pk.h[4] = f2bf(v1.x); pk.h[5] = f2bf(v1.y); pk.h[6] = f2bf(v1.z); pk.h[7] = f2bf(v1.w);
    *(f32x4*)((char*)lds + r * 256 + ((c ^ (r & 7)) << 4)) = pk.v;
  }
}

// ---------- kernel P: projection + quantization(+bitpack) + in-block f64 fix ----
__global__ __launch_bounds__(256) void k_proj(
    const float* __restrict__ Q, const float* __restrict__ K,
    const float* __restrict__ S, u16* __restrict__ Sqb, u8* __restrict__ Sgb,
    float* __restrict__ sn) {
  __shared__ __align__(16) u16 lds2[2 * 128 * 128];  // 64 KB, reused as f32 C-tile
  __shared__ u16 cbuf[CCAP];                          // 4 KB candidate list
  __shared__ u32 lcnt;
  u16* lA = lds2;
  u16* lB = lds2 + 128 * 128;
  const int tid = threadIdx.x;
  const int tile = blockIdx.x;           // 0..511 q, 512..1023 k
  const bool isK = (tile >= 512);
  const int row0 = (isK ? (tile - 512) : tile) * 128;
  const float* src = isK ? K : Q;

  if (tid == 0) lcnt = 0;

  stage_f32_to_bf16(S, lB, tid);
  stage_f32_to_bf16(src + (size_t)row0 * DD, lA, tid);

  // norms for K rows (rows are L1-hot from staging): 2 threads per row
  if (isK) {
    const int row = tid >> 1, half = tid & 1;
    const f32x4* base = (const f32x4*)(src + (size_t)(row0 + row) * DD) + half * 16;
    float s = 0.f;
#pragma unroll
    for (int j = 0; j < 16; ++j) {
      f32x4 v = base[j];
      s += v.x * v.x + v.y * v.y + v.z * v.z + v.w * v.w;
    }
    s += __shfl_xor(s, 1);
    if (half == 0) sn[row0 + row] = SCALE_F * sqrtf(s);
  }
  __syncthreads();

  const int wave = tid >> 6, lane = tid & 63;
  f32x4 acc[4][4];
#pragma unroll
  for (int a = 0; a < 4; ++a)
#pragma unroll
    for (int b = 0; b < 4; ++b) acc[a][b] = (f32x4){0.f, 0.f, 0.f, 0.f};

  mfma_tile(lA, lB, wave, lane, acc);

  // ---- epilogue: acc -> swizzled f32 LDS tile ----
  __syncthreads();                       // waves done reading lA/lB
  float* lc = (float*)lds2;              // 128x128 f32 = 64 KB
  const int wr = wave >> 1, wc = wave & 1;
#pragma unroll
  for (int a = 0; a < 4; ++a) {
#pragma unroll
    for (int b = 0; b < 4; ++b) {
      const int col = wc * 64 + b * 16 + (lane & 15);
#pragma unroll
      for (int j = 0; j < 4; ++j) {
        const int row = wr * 64 + a * 16 + (lane >> 4) * 4 + j;
        lc[row * 128 + (col ^ (((row >> 2) & 1) << 4))] = acc[a][b][j];
      }
    }
  }
  __syncthreads();

  // readback: thread owns 8 consecutive cols (c8) of rows rr, rr+16, ...
  const int c8 = tid & 15;
  const int rr = tid >> 4;
#pragma unroll
  for (int p = 0; p < 8; ++p) {
    const int row = rr + p * 16;
    const int s = (row >> 2) & 1;
    const int cb = (c8 ^ (s << 1)) * 8;          // swizzled element base
    f32x4 v0 = *(const f32x4*)&lc[row * 128 + cb];
    f32x4 v1 = *(const f32x4*)&lc[row * 128 + cb + 4];
    float vals[8] = {v0.x, v0.y, v0.z, v0.w, v1.x, v1.y, v1.z, v1.w};
    const int row_g = row0 + row;
    if (!isK) {
      union { u16 h[8]; f32x4 v; } pk;
#pragma unroll
      for (int e = 0; e < 8; ++e) pk.h[e] = f2bf(vals[e]);
      *(f32x4*)(Sqb + (size_t)row_g * MM + c8 * 8) = pk.v;
    } else {
      u32 byteval = 0;
#pragma unroll
      for (int e = 0; e < 8; ++e) {
        const int m = c8 * 8 + e;
        u32 bitneg = (vals[e] < 0.f) ? 1u : 0u;
        if (fabsf(vals[e]) < TAU) {
          u32 pos = atomicAdd(&lcnt, 1u);
          if (pos < CCAP) cbuf[pos] = (u16)((row << 8) | (bitneg << 7) | m);
          else bitneg = f64_negbit(K, S, row_g, m);  // overflow (~never)
        }
        byteval |= bitneg << e;
      }
      Sgb[(size_t)row_g * 16 + c8] = (u8)byteval;
    }
  }

  // ---- in-block f64 fix of borderline signs (K rows L1/L2-hot) ----
  if (isK) {
    __syncthreads();                     // cbuf/lcnt complete, byte stores drained
    __threadfence();                     // bytes visible before atomic RMW
    u32 n = lcnt; if (n > CCAP) n = CCAP;
    u32* Sg32 = (u32*)Sgb;
    for (u32 i = tid; i < n; i += 256) {
      u32 code = cbuf[i];
      int r = (code >> 8) & 127, m = code & 127;
      u32 prov = (code >> 7) & 1;
      u32 f64b = f64_negbit(K, S, row0 + r, m);
      if (f64b != prov)
        atomicXor(Sg32 + (size_t)(row0 + r) * 4 + (m >> 5), 1u << (m & 31));
    }
  }
}

// ---------- kernel G: out = (Sq @ sign^T) * sn[col], per head ----------
// A: global_load_lds dwordx4, pre-swizzled source / linear dest / swizzled read.
// B: packed sign bits (2 KB/tile, linear), unpacked to bf16 fragments via VALU.
// C: two 32 KB half-tile epilogues reusing A's LDS. Peak LDS ~34 KB -> 4 blk/CU.
__global__ __launch_bounds__(256, 4) void k_gemm(
    const u16* __restrict__ Sqb, const u8* __restrict__ Sgb,
    const float* __restrict__ sn, float* __restrict__ out) {
  __shared__ __align__(16) char smem[32768 + 2048];   // A/C-half | B-bits
  const u32* lBb = (const u32*)(smem + 32768);
  const int tid = threadIdx.x;
  const u32 id = blockIdx.x;                 // 0..8191
  const u32 l = (id & 7) * 1024 + (id >> 3); // bijective XCD-chunk swizzle
  const int tn = l & 15, tm = (l >> 4) & 15, bh = l >> 8;
  const char* Abase = (const char*)(Sqb + ((size_t)bh * SEQ + tm * 128) * MM);
  const char* Bbase = (const char*)(Sgb + ((size_t)bh * SEQ + tn * 128) * 16);

  {
    typedef __attribute__((address_space(3))) char lds_t;
    typedef const __attribute__((address_space(1))) char glob_t;
    const int wv = tid >> 6, ln = tid & 63;
#pragma unroll
    for (int j = 0; j < 8; ++j) {
      const int s = j * 256 + wv * 64 + ln;                 // dest chunk slot (linear)
      const int r = s >> 4, cp = s & 15;
      const int srcoff = r * 256 + ((cp ^ (r & 7)) << 4);   // pre-swizzled source
      __builtin_amdgcn_global_load_lds((glob_t*)(Abase + srcoff),
                                       (lds_t*)(smem + s * 16), 16, 0, 0);
    }
    if (tid < 128)
      __builtin_amdgcn_global_load_lds((glob_t*)(Bbase + tid * 16),
                                       (lds_t*)(smem + 32768 + tid * 16), 16, 0, 0);
  }
  __syncthreads();

  const int wave = tid >> 6, lane = tid & 63;
  const int wr = wave >> 1, wc = wave & 1;
  const int lrow = lane & 15, lkg = lane >> 4;
  f32x4 acc[4][4];
#pragma unroll
  for (int a = 0; a < 4; ++a)
#pragma unroll
    for (int b = 0; b < 4; ++b) acc[a][b] = (f32x4){0.f, 0.f, 0.f, 0.f};

#pragma unroll
  for (int kk = 0; kk < 4; ++kk) {
    const int c = kk * 4 + lkg;                  // 16B-chunk (A) / byte (B) index
    bf16x8 af[4], bfr[4];
#pragma unroll
    for (int a = 0; a < 4; ++a) {
      const int r = wr * 64 + a * 16 + lrow;
      af[a] = *(const bf16x8*)(smem + r * 256 + ((c ^ (r & 7)) << 4));
      const int r2 = wc * 64 + a * 16 + lrow;
      u32 word = lBb[r2 * 4 + kk];               // c>>2 == kk (broadcast in lkg)
      u32 byte = (word >> (lkg * 8)) & 0xFFu;    // c&3 == lkg
      union { u16 h[8]; bf16x8 v; } ub;
#pragma unroll
      for (int e = 0; e < 8; ++e) ub.h[e] = ((byte >> e) & 1u) ? 0xBF80 : 0x3F80;
      bfr[a] = ub.v;
    }
#pragma unroll
    for (int a = 0; a < 4; ++a)
#pragma unroll
      for (int b = 0; b < 4; ++b)
        acc[a][b] = __builtin_amdgcn_mfma_f32_16x16x32_bf16(af[a], bfr[b], acc[a][b], 0, 0, 0);
  }

  // ---- epilogue: two half-tiles (rows a=2h,2h+1 per wave) via 64x128 f32 LDS ----
  const float* snb = sn + bh * SEQ + tn * 128;
  const size_t outbase = (size_t)bh * SEQ * SEQ + (size_t)tm * 128 * SEQ + tn * 128;
  const int cch = tid & 31;              // f32x4 chunk within row
  const int hr0 = tid >> 5;              // rows hr0, hr0+8, ..., hr0+56
  const f32x4 s4 = *(const f32x4*)(snb + cch * 4);
  float* lc = (float*)smem;              // 64 x 128 f32 = 32 KB (reuses A)

#pragma unroll
  for (int h = 0; h < 2; ++h) {
    __syncthreads();                     // h=0: frag reads done; h=1: readback done
#pragma unroll
    for (int a2 = 0; a2 < 2; ++a2) {
      const int a = 2 * h + a2;
#pragma unroll
      for (int b = 0; b < 4; ++b) {
        const int col = wc * 64 + b * 16 + (lane & 15);
#pragma unroll
        for (int j = 0; j < 4; ++j) {
          const int hr = wr * 32 + a2 * 16 + (lane >> 4) * 4 + j;
          lc[hr * 128 + (col ^ (((hr >> 2) & 1) << 4))] = acc[a][b][j];
        }
      }
    }
    __syncthreads();
#pragma unroll
    for (int p = 0; p < 8; ++p) {
      const int hr = hr0 + p * 8;
      const int row = ((hr >> 5) << 6) + 32 * h + (hr & 31);
      const int cs = cch ^ (((hr >> 2) & 1) << 2);
      f32x4 v = *(const f32x4*)&lc[hr * 128 + cs * 4];
      v = v * s4;
      __builtin_nontemporal_store(v, (f32x4*)(out + outbase + (size_t)row * SEQ + cch * 4));
    }
  }
}

// ---------- launch ----------
extern "C" void kernel_launch(void* const* d_in, const int* in_sizes, int n_in,
                              void* d_out, int out_size, void* d_ws, size_t ws_size,
                              hipStream_t stream) {
  const float* q = (const float*)d_in[0];
  const float* k = (const float*)d_in[1];
  const float* S = (const float*)d_in[2];
  float* out = (float*)d_out;
  char* ws = (char*)d_ws;

  // workspace layout (bytes)
  const size_t off_Sq  = 0;                     // 65536*128*2 = 16 MiB
  const size_t off_Sg  = 16777216;              // 65536*16 B  =  1 MiB (bitmask)
  const size_t off_sn  = 17825792;              // 256 KiB

  u16*   Sqb = (u16*)(ws + off_Sq);
  u8*    Sgb = (u8*)(ws + off_Sg);
  float* sn  = (float*)(ws + off_sn);

  k_proj<<<1024, 256, 0, stream>>>(q, k, S, Sqb, Sgb, sn);
  k_gemm<<<8192, 256, 0, stream>>>(Sqb, Sgb, sn, out);
}